// Round 1
// baseline (338.978 us; speedup 1.0000x reference)
//
#include <hip/hip_runtime.h>

typedef __attribute__((ext_vector_type(8))) short short8;
typedef __attribute__((ext_vector_type(8))) unsigned short ushort8;
typedef __attribute__((ext_vector_type(4))) float f32x4;

__device__ __forceinline__ unsigned short f2bf(float f) {
  unsigned int u = __float_as_uint(f);
  u += 0x7fffu + ((u >> 16) & 1u);   // round-to-nearest-even
  return (unsigned short)(u >> 16);
}
__device__ __forceinline__ float bf2f(unsigned short u) {
  return __uint_as_float(((unsigned int)u) << 16);
}
__device__ __forceinline__ void gl_lds16(const void* g, void* l) {
  __builtin_amdgcn_global_load_lds(
      (const __attribute__((address_space(1))) unsigned int*)g,
      (__attribute__((address_space(3))) unsigned int*)l, 16, 0, 0);
}

// ---- prep: W1T2 [256 n'][256 k] bf16 (n'<128: W1a cols, n'>=128: W1b cols),
// ----       W1cT [128 n][32 k] bf16 (edge_attr weight, transposed),
// ----       b1s/W2s [128] f32 swizzled to fragment order: x[l15*8+ni] = X[ni*16+l15]
__global__ void prep_weights(const float* __restrict__ W1,
                             const float* __restrict__ b1,
                             const float* __restrict__ W2,
                             unsigned short* __restrict__ W1T2,
                             unsigned short* __restrict__ W1cT,
                             float* __restrict__ b1s,
                             float* __restrict__ W2s) {
  int idx = blockIdx.x * 256 + threadIdx.x;
  if (idx < 65536) {
    int np = idx >> 8, k = idx & 255;
    W1T2[idx] = f2bf(W1[(size_t)(k + ((np >> 7) << 8)) * 128 + (np & 127)]);
  } else if (idx < 69632) {
    int j = idx - 65536;
    int n = j >> 5, k = j & 31;
    W1cT[j] = f2bf(W1[(size_t)(512 + k) * 128 + n]);
  } else if (idx < 69760) {
    int j = idx - 69632;                    // b1s
    b1s[j] = b1[(j & 7) * 16 + (j >> 3)];
  } else if (idx < 69888) {
    int j = idx - 69760;                    // W2s
    W2s[j] = W2[(j & 7) * 16 + (j >> 3)];
  }
}

// ---- node projection: 128 nodes x 256 cols per block.
// ---- LDS layout is tile-major, lane-contiguous: 16x32 bf16 tile = 1024 B,
// ---- physical byte = tile*1024 + lane*16 where lane = quad*16 + l15,
// ---- logical (row = tile*16 + l15, k-chunk = quad). Both ds_write and
// ---- ds_read_b128 are contiguous 1 KB per wave -> zero bank conflicts.
// ---- Ps[node][256] bf16; within each 128-half, swizzled c' = (c&15)*8 + (c>>4)
__global__ __launch_bounds__(256, 2) void node_proj(
    const float* __restrict__ z, const unsigned short* __restrict__ W1T2,
    unsigned short* __restrict__ Ps, int NN) {
  __shared__ unsigned short As[2][128 * 32];   // 8 KB each  (8 tiles)
  __shared__ unsigned short Bs[2][256 * 32];   // 16 KB each (16 tiles)
  const int tid = threadIdx.x, wid = tid >> 6, lane = tid & 63;
  const int wrow = wid >> 1, wcol = wid & 1;
  const int quad = lane >> 4, l15 = lane & 15;
  const int bm = blockIdx.x;

  const float* zsrc[2];
#pragma unroll
  for (int j = 0; j < 2; ++j) {
    int row = (2 * wid + j) * 16 + l15;
    int node = min(bm * 128 + row, NN - 1);
    zsrc[j] = z + (size_t)node * 256;
  }

  f32x4 acc[4][8] = {};

  auto stage = [&](int ks, int bb) {
#pragma unroll
    for (int j = 0; j < 4; ++j) {
      int nb = 4 * wid + j;   // B tile 0..15; lane l -> row nb*16+(l&15), chunk l>>4
      gl_lds16(W1T2 + (size_t)(nb * 16 + l15) * 256 + ks * 32 + quad * 8,
               &Bs[bb][nb * 512]);
    }
#pragma unroll
    for (int j = 0; j < 2; ++j) {
      const float* gp = zsrc[j] + ks * 32 + quad * 8;
      f32x4 a = *(const f32x4*)gp;
      f32x4 c = *(const f32x4*)(gp + 4);
      ushort8 o;
      o[0]=f2bf(a[0]); o[1]=f2bf(a[1]); o[2]=f2bf(a[2]); o[3]=f2bf(a[3]);
      o[4]=f2bf(c[0]); o[5]=f2bf(c[1]); o[6]=f2bf(c[2]); o[7]=f2bf(c[3]);
      *(ushort8*)&As[bb][(2 * wid + j) * 512 + lane * 8] = o;   // contiguous
    }
  };

  auto compute = [&](int bb) {
    short8 af[4], bfv[8];
#pragma unroll
    for (int i = 0; i < 4; ++i)
      af[i] = *(const short8*)&As[bb][(wrow * 4 + i) * 512 + lane * 8];
#pragma unroll
    for (int i = 0; i < 8; ++i)
      bfv[i] = *(const short8*)&Bs[bb][(wcol * 8 + i) * 512 + lane * 8];
#pragma unroll
    for (int mi = 0; mi < 4; ++mi)
#pragma unroll
      for (int ni = 0; ni < 8; ++ni)
        acc[mi][ni] = __builtin_amdgcn_mfma_f32_16x16x32_bf16(af[mi], bfv[ni], acc[mi][ni], 0, 0, 0);
  };

  stage(0, 0);
#pragma unroll 1
  for (int s = 0; s < 8; ++s) {
    __syncthreads();
    if (s + 1 < 8) stage(s + 1, (s + 1) & 1);
    compute(s & 1);
  }

  // store: col C = wcol*128 + ni*16 + l15 -> Ps[node][wcol*128 + l15*8 + ni]
#pragma unroll
  for (int mi = 0; mi < 4; ++mi) {
#pragma unroll
    for (int r = 0; r < 4; ++r) {
      int row = wrow * 64 + mi * 16 + quad * 4 + r;
      int node = bm * 128 + row;
      if (node < NN) {
        ushort8 o;
#pragma unroll
        for (int ni = 0; ni < 8; ++ni) o[ni] = f2bf(acc[mi][ni][r]);
        *(ushort8*)&Ps[(size_t)node * 256 + wcol * 128 + l15 * 8] = o;
      }
    }
  }
}

// ---- edge kernel, NO LDS / NO barrier. One wave = 16 edges (one 16x16 tile):
// ---- per-thread live state halved vs 32-edge version so ALL 8 gathers can be
// ---- in flight simultaneously within the 128-VGPR budget (4 waves/SIMD).
__global__ __launch_bounds__(256, 4) void edge_pred(
    const int* __restrict__ eidx, const float* __restrict__ ea,
    const unsigned short* __restrict__ Ps, const unsigned short* __restrict__ W1cT,
    const float* __restrict__ b1s, const float* __restrict__ W2s,
    const float* __restrict__ b2, float* __restrict__ out, int E) {
  const int tid = threadIdx.x, wid = tid >> 6, lane = tid & 63;
  const int quad = lane >> 4, l15 = lane & 15;
  const int ebase = blockIdx.x * 64 + wid * 16;

  // 1) eidx first — longest dep chain (eidx -> gather -> epilogue).
  //    This thread's output rows are quad*4 + r, r=0..3.
  int srcn[4], dstn[4];
#pragma unroll
  for (int t = 0; t < 4; ++t) {
    int ec = min(ebase + quad * 4 + t, E - 1);
    srcn[t] = eidx[ec];
    dstn[t] = eidx[E + ec];
  }

  // 2) ea direct fragment load (non-temporal: streamed once, keep L2/L3 for Ps).
  //    A-frag: edge = ebase + l15, k = quad*8 + j
  const float* g = ea + (size_t)min(ebase + l15, E - 1) * 32 + quad * 8;
  f32x4 ealo = __builtin_nontemporal_load((const f32x4*)g);
  f32x4 eahi = __builtin_nontemporal_load((const f32x4*)(g + 4));

  // 3) W1c B-fragments direct from global (8 KB, L2-resident)
  short8 bfv[8];
#pragma unroll
  for (int ni = 0; ni < 8; ++ni)
    bfv[ni] = *(const short8*)&W1cT[(ni * 16 + l15) * 32 + quad * 8];

  // 4) P gathers (swizzled rows: 16B contiguous per lane) — all 8 in flight
  short8 p1[4], p2[4];
#pragma unroll
  for (int t = 0; t < 4; ++t) {
    p1[t] = *(const short8*)&Ps[(size_t)srcn[t] * 256 + l15 * 8];
    p2[t] = *(const short8*)&Ps[(size_t)dstn[t] * 256 + 128 + l15 * 8];
  }

  // 5) convert ea -> A-fragment
  ushort8 o;
  o[0]=f2bf(ealo[0]); o[1]=f2bf(ealo[1]); o[2]=f2bf(ealo[2]); o[3]=f2bf(ealo[3]);
  o[4]=f2bf(eahi[0]); o[5]=f2bf(eahi[1]); o[6]=f2bf(eahi[2]); o[7]=f2bf(eahi[3]);
  short8 af = (short8)o;

  // 6) MFMA (depends only on ea + Wc; gathers still in flight)
  f32x4 acc[8] = {};
#pragma unroll
  for (int ni = 0; ni < 8; ++ni)
    acc[ni] = __builtin_amdgcn_mfma_f32_16x16x32_bf16(af, bfv[ni], acc[ni], 0, 0, 0);

  // 7) epilogue constants (vectorized via prep-swizzled tables; loaded after the
  //    MFMA register-pressure peak, L2-resident)
  f32x4 b1a = *(const f32x4*)&b1s[l15 * 8];
  f32x4 b1b = *(const f32x4*)&b1s[l15 * 8 + 4];
  f32x4 w2a = *(const f32x4*)&W2s[l15 * 8];
  f32x4 w2b = *(const f32x4*)&W2s[l15 * 8 + 4];
  const float b2v = b2[0];

  // 8) epilogue: consume gathers (latency fully elapsed under MFMA)
#pragma unroll
  for (int r = 0; r < 4; ++r) {
    float p = 0.f;
#pragma unroll
    for (int ni = 0; ni < 8; ++ni) {
      float s = bf2f((unsigned short)p1[r][ni]) + bf2f((unsigned short)p2[r][ni]);
      float bb = (ni < 4) ? b1a[ni] : b1b[ni - 4];
      float ww = (ni < 4) ? w2a[ni] : w2b[ni - 4];
      float h = acc[ni][r] + s + bb;
      h = fmaxf(h, 0.f);
      p = fmaf(h, ww, p);
    }
    p += __shfl_xor(p, 1);
    p += __shfl_xor(p, 2);
    p += __shfl_xor(p, 4);
    p += __shfl_xor(p, 8);
    int e = ebase + quad * 4 + r;
    if (l15 == 0 && e < E) __builtin_nontemporal_store(p + b2v, &out[e]);
  }
}

extern "C" void kernel_launch(void* const* d_in, const int* in_sizes, int n_in,
                              void* d_out, int out_size, void* d_ws, size_t ws_size,
                              hipStream_t stream) {
  const float* z   = (const float*)d_in[0];
  const int*   eix = (const int*)d_in[1];
  const float* ea  = (const float*)d_in[2];
  const float* W1  = (const float*)d_in[3];
  const float* b1  = (const float*)d_in[4];
  const float* W2  = (const float*)d_in[5];
  const float* b2  = (const float*)d_in[6];
  float* out = (float*)d_out;

  const int E  = in_sizes[1] / 2;     // edge_label_index is [2, E]
  const int NN = in_sizes[0] / 256;   // nodes

  unsigned short* wsp = (unsigned short*)d_ws;
  unsigned short* Ps   = wsp;                               // NN*256 bf16 (51.2 MB)
  unsigned short* W1T2 = wsp + (size_t)NN * 256;            // 256*256 bf16
  unsigned short* W1cT = W1T2 + 65536;                      // 128*32 bf16
  float* b1s = (float*)(W1cT + 4096);                       // 128 f32 swizzled
  float* W2s = b1s + 128;                                   // 128 f32 swizzled

  prep_weights<<<273, 256, 0, stream>>>(W1, b1, W2, W1T2, W1cT, b1s, W2s);

  int nbm = (NN + 127) / 128;
  node_proj<<<nbm, 256, 0, stream>>>(z, W1T2, Ps, NN);

  int ge = (E + 63) / 64;
  edge_pred<<<ge, 256, 0, stream>>>(eix, ea, Ps, W1cT, b1s, W2s, b2, out, E);
}

// Round 2
// 333.366 us; speedup vs baseline: 1.0168x; 1.0168x over previous
//
#include <hip/hip_runtime.h>

typedef __attribute__((ext_vector_type(8))) short short8;
typedef __attribute__((ext_vector_type(8))) unsigned short ushort8;
typedef __attribute__((ext_vector_type(4))) float f32x4;

__device__ __forceinline__ unsigned short f2bf(float f) {
  unsigned int u = __float_as_uint(f);
  u += 0x7fffu + ((u >> 16) & 1u);   // round-to-nearest-even
  return (unsigned short)(u >> 16);
}
__device__ __forceinline__ float bf2f(unsigned short u) {
  return __uint_as_float(((unsigned int)u) << 16);
}
__device__ __forceinline__ void gl_lds16(const void* g, void* l) {
  __builtin_amdgcn_global_load_lds(
      (const __attribute__((address_space(1))) unsigned int*)g,
      (__attribute__((address_space(3))) unsigned int*)l, 16, 0, 0);
}

// ---- prep: W1T2 [256 n'][256 k] bf16 (n'<128: W1a cols, n'>=128: W1b cols),
// ----       W1cT [128 n][32 k] bf16 (edge_attr weight, transposed),
// ----       b1s/W2s [128] f32 swizzled to fragment order: x[l15*8+ni] = X[ni*16+l15]
__global__ void prep_weights(const float* __restrict__ W1,
                             const float* __restrict__ b1,
                             const float* __restrict__ W2,
                             unsigned short* __restrict__ W1T2,
                             unsigned short* __restrict__ W1cT,
                             float* __restrict__ b1s,
                             float* __restrict__ W2s) {
  int idx = blockIdx.x * 256 + threadIdx.x;
  if (idx < 65536) {
    int np = idx >> 8, k = idx & 255;
    W1T2[idx] = f2bf(W1[(size_t)(k + ((np >> 7) << 8)) * 128 + (np & 127)]);
  } else if (idx < 69632) {
    int j = idx - 65536;
    int n = j >> 5, k = j & 31;
    W1cT[j] = f2bf(W1[(size_t)(512 + k) * 128 + n]);
  } else if (idx < 69760) {
    int j = idx - 69632;                    // b1s
    b1s[j] = b1[(j & 7) * 16 + (j >> 3)];
  } else if (idx < 69888) {
    int j = idx - 69760;                    // W2s
    W2s[j] = W2[(j & 7) * 16 + (j >> 3)];
  }
}

// ---- node projection: 128 nodes x 256 cols per block.
// ---- LDS layout is tile-major, lane-contiguous: 16x32 bf16 tile = 1024 B,
// ---- physical byte = tile*1024 + lane*16 where lane = quad*16 + l15,
// ---- logical (row = tile*16 + l15, k-chunk = quad). Both ds_write and
// ---- ds_read_b128 are contiguous 1 KB per wave -> zero bank conflicts.
// ---- z is read ONCE per launch -> nontemporal, so it does not evict the
// ---- L3-resident gather working set (Ps + ea) that edge_pred depends on.
// ---- Ps[node][256] bf16; within each 128-half, swizzled c' = (c&15)*8 + (c>>4)
__global__ __launch_bounds__(256, 2) void node_proj(
    const float* __restrict__ z, const unsigned short* __restrict__ W1T2,
    unsigned short* __restrict__ Ps, int NN) {
  __shared__ unsigned short As[2][128 * 32];   // 8 KB each  (8 tiles)
  __shared__ unsigned short Bs[2][256 * 32];   // 16 KB each (16 tiles)
  const int tid = threadIdx.x, wid = tid >> 6, lane = tid & 63;
  const int wrow = wid >> 1, wcol = wid & 1;
  const int quad = lane >> 4, l15 = lane & 15;
  const int bm = blockIdx.x;

  const float* zsrc[2];
#pragma unroll
  for (int j = 0; j < 2; ++j) {
    int row = (2 * wid + j) * 16 + l15;
    int node = min(bm * 128 + row, NN - 1);
    zsrc[j] = z + (size_t)node * 256;
  }

  f32x4 acc[4][8] = {};

  auto stage = [&](int ks, int bb) {
#pragma unroll
    for (int j = 0; j < 4; ++j) {
      int nb = 4 * wid + j;   // B tile 0..15; lane l -> row nb*16+(l&15), chunk l>>4
      gl_lds16(W1T2 + (size_t)(nb * 16 + l15) * 256 + ks * 32 + quad * 8,
               &Bs[bb][nb * 512]);
    }
#pragma unroll
    for (int j = 0; j < 2; ++j) {
      const float* gp = zsrc[j] + ks * 32 + quad * 8;
      f32x4 a = __builtin_nontemporal_load((const f32x4*)gp);
      f32x4 c = __builtin_nontemporal_load((const f32x4*)(gp + 4));
      ushort8 o;
      o[0]=f2bf(a[0]); o[1]=f2bf(a[1]); o[2]=f2bf(a[2]); o[3]=f2bf(a[3]);
      o[4]=f2bf(c[0]); o[5]=f2bf(c[1]); o[6]=f2bf(c[2]); o[7]=f2bf(c[3]);
      *(ushort8*)&As[bb][(2 * wid + j) * 512 + lane * 8] = o;   // contiguous
    }
  };

  auto compute = [&](int bb) {
    short8 af[4], bfv[8];
#pragma unroll
    for (int i = 0; i < 4; ++i)
      af[i] = *(const short8*)&As[bb][(wrow * 4 + i) * 512 + lane * 8];
#pragma unroll
    for (int i = 0; i < 8; ++i)
      bfv[i] = *(const short8*)&Bs[bb][(wcol * 8 + i) * 512 + lane * 8];
#pragma unroll
    for (int mi = 0; mi < 4; ++mi)
#pragma unroll
      for (int ni = 0; ni < 8; ++ni)
        acc[mi][ni] = __builtin_amdgcn_mfma_f32_16x16x32_bf16(af[mi], bfv[ni], acc[mi][ni], 0, 0, 0);
  };

  stage(0, 0);
#pragma unroll 1
  for (int s = 0; s < 8; ++s) {
    __syncthreads();
    if (s + 1 < 8) stage(s + 1, (s + 1) & 1);
    compute(s & 1);
  }

  // store: col C = wcol*128 + ni*16 + l15 -> Ps[node][wcol*128 + l15*8 + ni]
#pragma unroll
  for (int mi = 0; mi < 4; ++mi) {
#pragma unroll
    for (int r = 0; r < 4; ++r) {
      int row = wrow * 64 + mi * 16 + quad * 4 + r;
      int node = bm * 128 + row;
      if (node < NN) {
        ushort8 o;
#pragma unroll
        for (int ni = 0; ni < 8; ++ni) o[ni] = f2bf(acc[mi][ni][r]);
        *(ushort8*)&Ps[(size_t)node * 256 + wcol * 128 + l15 * 8] = o;
      }
    }
  }
}

// ---- edge kernel, NO LDS / NO barrier. One wave = 16 edges (one 16x16 tile).
// ---- ea is loaded with NORMAL (cacheable) loads: Ps(51.2MB)+ea(128MB)+eidx(8MB)
// ---- +out(4MB) = 191MB < 256MB L3, so with z streamed NT the whole edge
// ---- working set stays Infinity-Cache-resident across iterations and the
// ---- random gathers stop falling through to HBM.
__global__ __launch_bounds__(256, 4) void edge_pred(
    const int* __restrict__ eidx, const float* __restrict__ ea,
    const unsigned short* __restrict__ Ps, const unsigned short* __restrict__ W1cT,
    const float* __restrict__ b1s, const float* __restrict__ W2s,
    const float* __restrict__ b2, float* __restrict__ out, int E) {
  const int tid = threadIdx.x, wid = tid >> 6, lane = tid & 63;
  const int quad = lane >> 4, l15 = lane & 15;
  const int ebase = blockIdx.x * 64 + wid * 16;

  // 1) eidx first — longest dep chain (eidx -> gather -> epilogue).
  //    This thread's output rows are quad*4 + r, r=0..3.
  int srcn[4], dstn[4];
#pragma unroll
  for (int t = 0; t < 4; ++t) {
    int ec = min(ebase + quad * 4 + t, E - 1);
    srcn[t] = eidx[ec];
    dstn[t] = eidx[E + ec];
  }

  // 2) ea fragment load (cacheable — L3-resident across iterations).
  //    A-frag: edge = ebase + l15, k = quad*8 + j
  const float* g = ea + (size_t)min(ebase + l15, E - 1) * 32 + quad * 8;
  f32x4 ealo = *(const f32x4*)g;
  f32x4 eahi = *(const f32x4*)(g + 4);

  // 3) W1c B-fragments direct from global (8 KB, L2-resident)
  short8 bfv[8];
#pragma unroll
  for (int ni = 0; ni < 8; ++ni)
    bfv[ni] = *(const short8*)&W1cT[(ni * 16 + l15) * 32 + quad * 8];

  // 4) P gathers (swizzled rows: 16B contiguous per lane) — all 8 in flight
  short8 p1[4], p2[4];
#pragma unroll
  for (int t = 0; t < 4; ++t) {
    p1[t] = *(const short8*)&Ps[(size_t)srcn[t] * 256 + l15 * 8];
    p2[t] = *(const short8*)&Ps[(size_t)dstn[t] * 256 + 128 + l15 * 8];
  }

  // 5) convert ea -> A-fragment
  ushort8 o;
  o[0]=f2bf(ealo[0]); o[1]=f2bf(ealo[1]); o[2]=f2bf(ealo[2]); o[3]=f2bf(ealo[3]);
  o[4]=f2bf(eahi[0]); o[5]=f2bf(eahi[1]); o[6]=f2bf(eahi[2]); o[7]=f2bf(eahi[3]);
  short8 af = (short8)o;

  // 6) MFMA (depends only on ea + Wc; gathers still in flight)
  f32x4 acc[8] = {};
#pragma unroll
  for (int ni = 0; ni < 8; ++ni)
    acc[ni] = __builtin_amdgcn_mfma_f32_16x16x32_bf16(af, bfv[ni], acc[ni], 0, 0, 0);

  // 7) epilogue constants (vectorized via prep-swizzled tables; loaded after the
  //    MFMA register-pressure peak, L2-resident)
  f32x4 b1a = *(const f32x4*)&b1s[l15 * 8];
  f32x4 b1b = *(const f32x4*)&b1s[l15 * 8 + 4];
  f32x4 w2a = *(const f32x4*)&W2s[l15 * 8];
  f32x4 w2b = *(const f32x4*)&W2s[l15 * 8 + 4];
  const float b2v = b2[0];

  // 8) epilogue: consume gathers (latency fully elapsed under MFMA)
#pragma unroll
  for (int r = 0; r < 4; ++r) {
    float p = 0.f;
#pragma unroll
    for (int ni = 0; ni < 8; ++ni) {
      float s = bf2f((unsigned short)p1[r][ni]) + bf2f((unsigned short)p2[r][ni]);
      float bb = (ni < 4) ? b1a[ni] : b1b[ni - 4];
      float ww = (ni < 4) ? w2a[ni] : w2b[ni - 4];
      float h = acc[ni][r] + s + bb;
      h = fmaxf(h, 0.f);
      p = fmaf(h, ww, p);
    }
    p += __shfl_xor(p, 1);
    p += __shfl_xor(p, 2);
    p += __shfl_xor(p, 4);
    p += __shfl_xor(p, 8);
    int e = ebase + quad * 4 + r;
    if (l15 == 0 && e < E) __builtin_nontemporal_store(p + b2v, &out[e]);
  }
}

extern "C" void kernel_launch(void* const* d_in, const int* in_sizes, int n_in,
                              void* d_out, int out_size, void* d_ws, size_t ws_size,
                              hipStream_t stream) {
  const float* z   = (const float*)d_in[0];
  const int*   eix = (const int*)d_in[1];
  const float* ea  = (const float*)d_in[2];
  const float* W1  = (const float*)d_in[3];
  const float* b1  = (const float*)d_in[4];
  const float* W2  = (const float*)d_in[5];
  const float* b2  = (const float*)d_in[6];
  float* out = (float*)d_out;

  const int E  = in_sizes[1] / 2;     // edge_label_index is [2, E]
  const int NN = in_sizes[0] / 256;   // nodes

  unsigned short* wsp = (unsigned short*)d_ws;
  unsigned short* Ps   = wsp;                               // NN*256 bf16 (51.2 MB)
  unsigned short* W1T2 = wsp + (size_t)NN * 256;            // 256*256 bf16
  unsigned short* W1cT = W1T2 + 65536;                      // 128*32 bf16
  float* b1s = (float*)(W1cT + 4096);                       // 128 f32 swizzled
  float* W2s = b1s + 128;                                   // 128 f32 swizzled

  prep_weights<<<273, 256, 0, stream>>>(W1, b1, W2, W1T2, W1cT, b1s, W2s);

  int nbm = (NN + 127) / 128;
  node_proj<<<nbm, 256, 0, stream>>>(z, W1T2, Ps, NN);

  int ge = (E + 63) / 64;
  edge_pred<<<ge, 256, 0, stream>>>(eix, ea, Ps, W1cT, b1s, W2s, b2, out, E);
}